// Round 2
// baseline (210.074 us; speedup 1.0000x reference)
//
#include <hip/hip_runtime.h>

#define DIMB 2
#define DIMS 192
#define DPT 6        // d-outputs per thread
#define TX 32        // threads in d: 32*6 = 192 (full d extent per block)
#define TY 8         // w rows per block
#define HCHUNK 6     // h rows per block (32 chunks cover 192)

// 4-float vector with only 4-byte alignment: gfx950 supports misaligned
// global_load_dwordx4 (unaligned-access-mode), so this stays one instruction.
typedef float f4a __attribute__((ext_vector_type(4), aligned(4)));

// Compute 3x3 (w,d)-plane sums of the 5 product channels at row hh for the
// DPT output voxels d0..d0+5 owned by this thread. Zero padding at all edges.
__device__ __forceinline__ void compute_plane(
    const float* __restrict__ pred, const float* __restrict__ targ,
    int b, int hh, int w, int tx, float (&out)[5][DPT])
{
#pragma unroll
    for (int c = 0; c < 5; ++c)
#pragma unroll
        for (int j = 0; j < DPT; ++j) out[c][j] = 0.f;
    if (hh < 0 || hh >= DIMS) return;

    const int d0 = tx * DPT;
    // window needs d0-1 .. d0+6 (8 values) = two float4s at d0-1 and d0+3.
    // Global d-edges: shift within the register instead of loading OOB.
    const int lo_off = (tx == 0)      ? 0       : d0 - 1;
    const int hi_off = (tx == TX - 1) ? d0 + 2  : d0 + 3;

#pragma unroll
    for (int dw = -1; dw <= 1; ++dw) {
        const int wc = w + dw;
        if (wc < 0 || wc >= DIMS) continue;
        const size_t rb = (((size_t)b * DIMS + hh) * DIMS + wc) * DIMS;
        f4a pa = *reinterpret_cast<const f4a*>(pred + rb + lo_off);
        f4a pb = *reinterpret_cast<const f4a*>(pred + rb + hi_off);
        f4a ta = *reinterpret_cast<const f4a*>(targ + rb + lo_off);
        f4a tb = *reinterpret_cast<const f4a*>(targ + rb + hi_off);
        if (tx == 0) {          // window starts at pad: (0, v0, v1, v2)
            pa = (f4a){0.f, pa.x, pa.y, pa.z};
            ta = (f4a){0.f, ta.x, ta.y, ta.z};
        }
        if (tx == TX - 1) {     // window ends at pad: (v1, v2, v3, 0)
            pb = (f4a){pb.y, pb.z, pb.w, 0.f};
            tb = (f4a){tb.y, tb.z, tb.w, 0.f};
        }
        float pv[8] = {pa.x, pa.y, pa.z, pa.w, pb.x, pb.y, pb.z, pb.w};
        float tv[8] = {ta.x, ta.y, ta.z, ta.w, tb.x, tb.y, tb.z, tb.w};
        float pp[8], tt[8], pt[8];
#pragma unroll
        for (int k = 0; k < 8; ++k) {
            pp[k] = pv[k] * pv[k];
            tt[k] = tv[k] * tv[k];
            pt[k] = pv[k] * tv[k];
        }
#pragma unroll
        for (int j = 0; j < DPT; ++j) {
            out[0][j] += pv[j] + pv[j+1] + pv[j+2];
            out[1][j] += tv[j] + tv[j+1] + tv[j+2];
            out[2][j] += pp[j] + pp[j+1] + pp[j+2];
            out[3][j] += tt[j] + tt[j+1] + tt[j+2];
            out[4][j] += pt[j] + pt[j+1] + pt[j+2];
        }
    }
}

// One output row h: compute plane(h+1) into Pn, emit ncc for the DPT voxels.
__device__ __forceinline__ float do_row(
    const float* __restrict__ pred, const float* __restrict__ targ,
    int b, int h, int w, int tx,
    float (&Pm)[5][DPT], float (&Pc)[5][DPT], float (&Pn)[5][DPT])
{
    compute_plane(pred, targ, b, h + 1, w, tx, Pn);
    const float inv = 1.0f / 27.0f;
    float acc = 0.f;
#pragma unroll
    for (int j = 0; j < DPT; ++j) {
        const float sI  = Pm[0][j] + Pc[0][j] + Pn[0][j];
        const float sJ  = Pm[1][j] + Pc[1][j] + Pn[1][j];
        const float sII = Pm[2][j] + Pc[2][j] + Pn[2][j];
        const float sJJ = Pm[3][j] + Pc[3][j] + Pn[3][j];
        const float sIJ = Pm[4][j] + Pc[4][j] + Pn[4][j];
        const float uI = sI * inv;
        const float uJ = sJ * inv;
        const float cross = sIJ - uI * sJ;
        const float pvar  = sII - uI * sI;
        const float tvar  = sJJ - uJ * sJ;
        acc += (cross * cross) * __builtin_amdgcn_rcpf(tvar * pvar + 1e-5f);
    }
    return acc;
}

__global__ __launch_bounds__(256)
void FusedLocalNormalizedCrossCorrelationLoss_37838661877790_kernel(
    const float* __restrict__ pred, const float* __restrict__ targ,
    double* __restrict__ acc_out)
{
    const int tx = threadIdx.x;              // 32 d-sextets
    const int ty = threadIdx.y;              // 8 w rows
    const int w  = blockIdx.y * TY + ty;
    const int bz = blockIdx.z;
    const int b  = bz >> 5;                  // 2 batches
    const int h0 = (bz & 31) * HCHUNK;       // 32 h-chunks

    float P[3][5][DPT];
    compute_plane(pred, targ, b, h0 - 1, w, tx, P[0]);
    compute_plane(pred, targ, b, h0,     w, tx, P[1]);

    float acc = 0.f;
#pragma unroll
    for (int hb = 0; hb < HCHUNK; hb += 3) {
        acc += do_row(pred, targ, b, h0 + hb,     w, tx, P[0], P[1], P[2]);
        acc += do_row(pred, targ, b, h0 + hb + 1, w, tx, P[1], P[2], P[0]);
        acc += do_row(pred, targ, b, h0 + hb + 2, w, tx, P[2], P[0], P[1]);
    }

    // Reduction: wave shuffle tree -> LDS -> one fp64 atomic per block.
#pragma unroll
    for (int off = 32; off > 0; off >>= 1)
        acc += __shfl_down(acc, off, 64);
    __shared__ float wacc[4];
    const int tid = ty * TX + tx;
    if ((tid & 63) == 0) wacc[tid >> 6] = acc;
    __syncthreads();
    if (tid == 0) {
        const double s = (double)wacc[0] + (double)wacc[1]
                       + (double)wacc[2] + (double)wacc[3];
        atomicAdd(acc_out, s);
    }
}

__global__ void ncc_finalize(const double* __restrict__ acc,
                             float* __restrict__ out)
{
    const double n = (double)((size_t)DIMB * DIMS * DIMS * DIMS);
    out[0] = (float)(-acc[0] / n);
}

extern "C" void kernel_launch(void* const* d_in, const int* in_sizes, int n_in,
                              void* d_out, int out_size, void* d_ws, size_t ws_size,
                              hipStream_t stream) {
    const float* pred = (const float*)d_in[0];
    const float* targ = (const float*)d_in[1];
    double* acc = (double*)d_ws;

    hipMemsetAsync(d_ws, 0, sizeof(double), stream);

    dim3 block(TX, TY, 1);
    dim3 grid(1, DIMS / TY, DIMB * (DIMS / HCHUNK));  // 1 x 24 x 64 = 1536 blocks
    FusedLocalNormalizedCrossCorrelationLoss_37838661877790_kernel
        <<<grid, block, 0, stream>>>(pred, targ, acc);
    ncc_finalize<<<1, 1, 0, stream>>>(acc, (float*)d_out);
}